// Round 8
// baseline (175.927 us; speedup 1.0000x reference)
//
#include <hip/hip_runtime.h>
#include <hip/hip_bf16.h>
#include <stdint.h>

// LoRAExpert: out = ragged_dot(x, W, groups) + scale[a] * ((x @ A[a,e]) @ B[a,e])
// T=8192, D_IN=D_OUT=1024, E=8 (equal groups of 1024), A=4 adapters, R=16.
// Inputs fp32, output fp32. ws = 256 MiB.
//
// Round 13: fold V = x @ (s*lora_A[e]) INTO k_gemm (the xva phase was the
// serialization hot-spot: 12% HBM, 1% MFMA). k_gemm already stages every
// x A-tile in LDS; V accumulates alongside the main GEMM reusing af[mi]
// against Aoct B-frags read directly from global (Aoct = 1MB, L2-resident).
// Tail kt=16: masked V -> bf16 -> As LDS in the swizzled layout the tail
// fragment reads expect; B = Boct octs 128..135 as before. MFMA chain for
// V is bit-identical to the old xva (same order, same rounding).
//   k_prepA : lora_A -> Aoct (scale folded). 256 blocks.
//   k_main  : PURE STREAMING now: blocks [0,1024) x->xp (stride 1024),
//             [1024,2048) W->Boct, [2048,2112) lora_B->Boct.
//   k_gemm  : out = [x|V](K=1088) @ Boct[e]; 128x128, double K-step,
//             V fused, XOR-swizzled A LDS, gload_lds w16, XCD swizzle.

#define T_TOK 8192
#define DIN   1024
#define DOUT  1024
#define NE    8
#define NA    4
#define RK    16
#define NOCT  136       // 128 (W) + 8 (lora_B) K-octs

typedef __attribute__((ext_vector_type(8))) short short8;
typedef __attribute__((ext_vector_type(4))) float f32x4;

__device__ __forceinline__ ushort f2bf(float f) {
  union { float f; uint32_t i; } v; v.f = f;
  uint32_t x = v.i;
  return (ushort)((x + 0x7fffu + ((x >> 16) & 1u)) >> 16);  // RNE
}

__device__ __forceinline__ void gload_lds16(const void* g, void* l) {
  __builtin_amdgcn_global_load_lds(
      (const __attribute__((address_space(1))) uint32_t*)g,
      (__attribute__((address_space(3))) uint32_t*)l,
      16, 0, 0);
}

__device__ __forceinline__ int expert_of_row(const int* __restrict__ gs, int row) {
  int cum = 0, e = 0;
#pragma unroll
  for (int i = 0; i < NE; ++i) { if (row >= cum) e = i; cum += gs[i]; }
  return e;
}

// ---- k_prepA: lora_A -> Aoct[e][ko][c][8], scale folded. 256 blocks. ----
// Aoct[(e*128+ko)*64 + c] oct j = s_a * lora_A[a][e][ko*8+j][r], c = a*16+r.
__global__ __launch_bounds__(256) void k_prepA(
    const float* __restrict__ lora_A, const float* __restrict__ lora_scaling,
    ushort* __restrict__ Aoct) {
  const int bid = blockIdx.x;
  const int tid = threadIdx.x;
  int u = bid * 4 + (tid >> 6);         // 0..1023 = e*128+ko
  int e = u >> 7, ko = u & 127;
  int c = tid & 63;
  int a = c >> 4, r = c & 15;
  float s = lora_scaling[a];
  ushort o8[8];
#pragma unroll
  for (int j = 0; j < 8; ++j) {
    float v = lora_A[((size_t)(a * NE + e) * DIN + ko * 8 + j) * RK + r];
    o8[j] = f2bf(s * v);
  }
  *(uint4*)(Aoct + ((size_t)((e * 128 + ko) * 64 + c)) * 8) = *(const uint4*)o8;
}

// ---- k_main: pure streaming packs ----
// blocks [0,1024)    : x fp32 -> xp bf16 (stride 1024, straight copy-convert)
// blocks [1024,2048) : W -> Boct[e][ko<128][n][8]
// blocks [2048,2112) : lora_B -> Boct[e][128+o][n][8]
__global__ __launch_bounds__(256) void k_main(
    const float* __restrict__ x, ushort* __restrict__ xp,
    const float* __restrict__ weight, const float* __restrict__ lora_B,
    ushort* __restrict__ Boct) {
  const int bid = blockIdx.x;
  const int tid = threadIdx.x;

  if (bid < 1024) {
    // ======== pack x: 8 float4/thread, per-instruction coalesced ========
#pragma unroll
    for (int i = 0; i < 8; ++i) {
      int u = bid * 2048 + i * 256 + tid;         // float4 index
      float4 v = ((const float4*)x)[u];
      ushort4 b;
      b.x = f2bf(v.x); b.y = f2bf(v.y); b.z = f2bf(v.z); b.w = f2bf(v.w);
      ((ushort4*)xp)[u] = b;
    }
  } else {
    // ======== Boct pack ========
    int e, ko;
    const float* srcbase = nullptr;
    if (bid < 2048) {                     // W rows
      int u = bid - 1024;                 // 0..1023
      e = u >> 7; ko = u & 127;
      srcbase = weight + (size_t)e * DIN * DOUT + (size_t)(ko * 8) * DOUT;
    } else {                              // lora_B rows
      int u = bid - 2048;                 // 0..63
      e = u >> 3; int o = u & 7; ko = 128 + o;
    }
    int n4 = tid * 4;
    float v[8][4];
    if (bid < 2048) {
#pragma unroll
      for (int j = 0; j < 8; ++j) {
        float4 q = *(const float4*)(srcbase + (size_t)j * DOUT + n4);
        v[j][0] = q.x; v[j][1] = q.y; v[j][2] = q.z; v[j][3] = q.w;
      }
    } else {
      int o = ko - 128;
#pragma unroll
      for (int j = 0; j < 8; ++j) {
        int kv = o * 8 + j;
        int a = kv >> 4, r = kv & 15;
        float4 q = *(const float4*)(lora_B + (size_t)((a * NE + e) * RK + r) * DOUT + n4);
        v[j][0] = q.x; v[j][1] = q.y; v[j][2] = q.z; v[j][3] = q.w;
      }
    }
    ushort* dst = Boct + ((size_t)(e * NOCT + ko) * DOUT + n4) * 8;
#pragma unroll
    for (int i = 0; i < 4; ++i) {
      ushort o8[8];
#pragma unroll
      for (int j = 0; j < 8; ++j) o8[j] = f2bf(v[j][i]);
      *(uint4*)(dst + i * 8) = *(const uint4*)o8;
    }
  }
}

// ---- k_gemm: out[128x128] = [x|V](128 x 1088) @ Boct[e](1088 x 128) ----
// Double K-step (2 x BK=64 per barrier pair), V fused into the main loop.
__global__ __launch_bounds__(256) void k_gemm(
    const ushort* __restrict__ xp, const ushort* __restrict__ Boct,
    const ushort* __restrict__ Aoct,
    const int* __restrict__ gs, const int* __restrict__ adapter_idx,
    float* __restrict__ out) {
  __shared__ ushort As[2][128 * 64];      // 32 KB
  __shared__ ushort Bs[2][8 * 128 * 8];   // 32 KB

  const int tid = threadIdx.x;
  const int lane = tid & 63;
  const int wave = tid >> 6;
  const int wm = wave >> 1, wn = wave & 1;

  const int bid = blockIdx.x;                 // 0..511
  const int swz = (bid & 7) * 64 + (bid >> 3);  // bijective (512 % 8 == 0)
  const int row0 = (swz >> 3) * 128;
  const int n0 = (swz & 7) * 128;
  const int e = expert_of_row(gs, row0);
  const ushort* boct = Boct + (size_t)e * NOCT * DOUT * 8;
  const ushort* aocte = Aoct + (size_t)e * 128 * 64 * 8;

  f32x4 acc[4][4];
  f32x4 vacc[4][2];
#pragma unroll
  for (int mi = 0; mi < 4; ++mi) {
#pragma unroll
    for (int ni = 0; ni < 4; ++ni) acc[mi][ni] = (f32x4){0.f, 0.f, 0.f, 0.f};
    vacc[mi][0] = (f32x4){0.f, 0.f, 0.f, 0.f};
    vacc[mi][1] = (f32x4){0.f, 0.f, 0.f, 0.f};
  }

  const int r8 = lane >> 3;
  const int c8s = (lane & 7) ^ r8;              // swizzled source chunk

  // stage one BK=64 tile (kt in 0..15) into buffer hb
#define STAGE_TILE(hb, kt)                                                     \
  do {                                                                         \
    _Pragma("unroll")                                                          \
    for (int rd = 0; rd < 4; ++rd) {                                           \
      int r_ = wave * 32 + rd * 8 + r8;                                        \
      const ushort* src_ = xp + (size_t)(row0 + r_) * DIN + (kt) * 64 + c8s * 8; \
      gload_lds16(src_, &As[hb][(wave * 32 + rd * 8) * 64]);                   \
    }                                                                          \
    _Pragma("unroll")                                                          \
    for (int rd = 0; rd < 4; ++rd) {                                           \
      int u_ = wave * 4 + rd;                                                  \
      int o_ = u_ >> 1, hf_ = u_ & 1;                                          \
      const ushort* src_ =                                                     \
          boct + ((size_t)((kt) * 8 + o_) * DOUT + n0 + hf_ * 64 + lane) * 8;  \
      gload_lds16(src_, &Bs[hb][(o_ * 128 + hf_ * 64) * 8]);                   \
    }                                                                          \
  } while (0)

  // compute one BK=64 tile from buffer hb: main GEMM + fused V accumulation
#define COMPUTE_TILE(hb, kt)                                                   \
  do {                                                                         \
    _Pragma("unroll")                                                          \
    for (int h = 0; h < 2; ++h) {                                              \
      int kblk = h * 4 + (lane >> 4);                                          \
      /* V B-frags from global (L2-resident Aoct) -- issue first */            \
      short8 av0 = *(const short8*)(aocte +                                    \
          ((size_t)((kt) * 8 + kblk) * 64 + wn * 32 + (lane & 15)) * 8);       \
      short8 av1 = *(const short8*)(aocte +                                    \
          ((size_t)((kt) * 8 + kblk) * 64 + wn * 32 + 16 + (lane & 15)) * 8);  \
      short8 af[4], bfv[4];                                                    \
      _Pragma("unroll")                                                        \
      for (int mi = 0; mi < 4; ++mi) {                                         \
        int m_ = wm * 64 + mi * 16 + (lane & 15);                              \
        af[mi] = *(const short8*)&As[hb][m_ * 64 + (kblk ^ (m_ & 7)) * 8];     \
      }                                                                        \
      _Pragma("unroll")                                                        \
      for (int ni = 0; ni < 4; ++ni) {                                         \
        int n_ = wn * 64 + ni * 16 + (lane & 15);                              \
        bfv[ni] = *(const short8*)&Bs[hb][(kblk * 128 + n_) * 8];              \
      }                                                                        \
      _Pragma("unroll")                                                        \
      for (int mi = 0; mi < 4; ++mi)                                           \
        _Pragma("unroll")                                                      \
        for (int ni = 0; ni < 4; ++ni)                                         \
          acc[mi][ni] = __builtin_amdgcn_mfma_f32_16x16x32_bf16(               \
              af[mi], bfv[ni], acc[mi][ni], 0, 0, 0);                          \
      _Pragma("unroll")                                                        \
      for (int mi = 0; mi < 4; ++mi) {                                         \
        vacc[mi][0] = __builtin_amdgcn_mfma_f32_16x16x32_bf16(                 \
            af[mi], av0, vacc[mi][0], 0, 0, 0);                                \
        vacc[mi][1] = __builtin_amdgcn_mfma_f32_16x16x32_bf16(                 \
            af[mi], av1, vacc[mi][1], 0, 0, 0);                                \
      }                                                                        \
    }                                                                          \
  } while (0)

  for (int kp = 0; kp < 8; ++kp) {
    STAGE_TILE(0, kp * 2);
    STAGE_TILE(1, kp * 2 + 1);
    __syncthreads();
    COMPUTE_TILE(0, kp * 2);
    COMPUTE_TILE(1, kp * 2 + 1);
    __syncthreads();
  }

#undef STAGE_TILE
#undef COMPUTE_TILE

  // ---- V tail (kt = 16) ----
  // stage B tail octs (global ko = 128..135) into Bs[0]
#pragma unroll
  for (int rd = 0; rd < 4; ++rd) {
    int u = wave * 4 + rd;
    int o = u >> 1, hf = u & 1;
    const ushort* src = boct + ((size_t)(128 + o) * DOUT + n0 + hf * 64 + lane) * 8;
    gload_lds16(src, &Bs[0][(o * 128 + hf * 64) * 8]);
  }
  // write masked V (bf16) into As[0] with the XOR-swizzled layout:
  // LDS[row][cslot][j] = V[row][c], cslot = (c>>3)^(row&7), j = c&7
#pragma unroll
  for (int mi = 0; mi < 4; ++mi) {
#pragma unroll
    for (int i = 0; i < 4; ++i) {
      int rl = wm * 64 + mi * 16 + (lane >> 4) * 4 + i;
      int arow = adapter_idx[row0 + rl];
#pragma unroll
      for (int vi = 0; vi < 2; ++vi) {
        int c = wn * 32 + vi * 16 + (lane & 15);
        float val = (arow == (wn * 2 + vi)) ? vacc[mi][vi][i] : 0.f;
        As[0][rl * 64 + (((c >> 3) ^ (rl & 7)) * 8) + (c & 7)] = f2bf(val);
      }
    }
  }
  __syncthreads();

  // tail compute: A = V (K=64) from As[0], B = Bs[0]
#pragma unroll
  for (int h = 0; h < 2; ++h) {
    int kblk = h * 4 + (lane >> 4);
    short8 af[4], bfv[4];
#pragma unroll
    for (int mi = 0; mi < 4; ++mi) {
      int m = wm * 64 + mi * 16 + (lane & 15);
      af[mi] = *(const short8*)&As[0][m * 64 + (kblk ^ (m & 7)) * 8];
    }
#pragma unroll
    for (int ni = 0; ni < 4; ++ni) {
      int n = wn * 64 + ni * 16 + (lane & 15);
      bfv[ni] = *(const short8*)&Bs[0][(kblk * 128 + n) * 8];
    }
#pragma unroll
    for (int mi = 0; mi < 4; ++mi)
#pragma unroll
      for (int ni = 0; ni < 4; ++ni)
        acc[mi][ni] = __builtin_amdgcn_mfma_f32_16x16x32_bf16(
            af[mi], bfv[ni], acc[mi][ni], 0, 0, 0);
  }

  // epilogue: C layout col=lane&15, row=(lane>>4)*4+reg
#pragma unroll
  for (int mi = 0; mi < 4; ++mi) {
#pragma unroll
    for (int ni = 0; ni < 4; ++ni) {
      int col = n0 + wn * 64 + ni * 16 + (lane & 15);
#pragma unroll
      for (int i = 0; i < 4; ++i) {
        int r = row0 + wm * 64 + mi * 16 + (lane >> 4) * 4 + i;
        out[(size_t)r * DOUT + col] = acc[mi][ni][i];
      }
    }
  }
}

extern "C" void kernel_launch(void* const* d_in, const int* in_sizes, int n_in,
                              void* d_out, int out_size, void* d_ws, size_t ws_size,
                              hipStream_t stream) {
  const float* x            = (const float*)d_in[0];
  const float* weight       = (const float*)d_in[1];
  const float* lora_A       = (const float*)d_in[2];
  const float* lora_B       = (const float*)d_in[3];
  const float* lora_scaling = (const float*)d_in[4];
  const int*   group_sizes  = (const int*)d_in[5];
  const int*   adapter_idx  = (const int*)d_in[6];
  float* out = (float*)d_out;

  const size_t sz_xp   = (size_t)T_TOK * DIN * 2;               // 16.8 MB
  const size_t sz_boct = (size_t)NE * NOCT * DOUT * 8 * 2;      // 17.8 MB
  ushort* xp   = (ushort*)d_ws;
  ushort* boct = (ushort*)((char*)d_ws + sz_xp);
  ushort* aoct = (ushort*)((char*)d_ws + sz_xp + sz_boct);      // 1 MB

  k_prepA<<<256, 256, 0, stream>>>(lora_A, lora_scaling, aoct);
  k_main<<<2112, 256, 0, stream>>>(x, xp, weight, lora_B, boct);
  k_gemm<<<512, 256, 0, stream>>>(xp, boct, aoct, group_sizes, adapter_idx, out);
}

// Round 9
// 170.234 us; speedup vs baseline: 1.0334x; 1.0334x over previous
//
#include <hip/hip_runtime.h>
#include <hip/hip_bf16.h>
#include <stdint.h>

// LoRAExpert: out = ragged_dot(x, W, groups) + scale[a] * ((x @ A[a,e]) @ B[a,e])
// T=8192, D_IN=D_OUT=1024, E=8 (equal groups of 1024), A=4 adapters, R=16.
// Inputs fp32, output fp32. ws = 256 MiB.
//
// Round 14: R13 post-mortem -- fused-V was right, but the Aoct B-frag global
// loads sat INSIDE the compute phase (k_gemm 56us, MfmaUtil 17%, naked L2
// stalls at 2 waves/SIMD). T14 fix: prefetch the 8 short8 V-fragments to
// REGISTERS during the stage phase (issued after the gload_lds volley,
// drained by the same pre-barrier vmcnt the staging already pays). Compute
// phase is pure {ds_read + MFMA} again. Everything else identical to R13
// (which passed correctness): pure-streaming k_main, V tail via swizzled
// LDS write, XCD swizzle, double K-step.
//   k_prepA : lora_A -> Aoct (scale folded). 256 blocks.
//   k_main  : pure streaming: [0,1024) x->xp, [1024,2048) W->Boct,
//             [2048,2112) lora_B->Boct.
//   k_gemm  : out = [x|V](K=1088) @ Boct[e]; 128x128, double K-step,
//             V fused w/ register-prefetched Aoct frags.

#define T_TOK 8192
#define DIN   1024
#define DOUT  1024
#define NE    8
#define NA    4
#define RK    16
#define NOCT  136       // 128 (W) + 8 (lora_B) K-octs

typedef __attribute__((ext_vector_type(8))) short short8;
typedef __attribute__((ext_vector_type(4))) float f32x4;

__device__ __forceinline__ ushort f2bf(float f) {
  union { float f; uint32_t i; } v; v.f = f;
  uint32_t x = v.i;
  return (ushort)((x + 0x7fffu + ((x >> 16) & 1u)) >> 16);  // RNE
}

__device__ __forceinline__ void gload_lds16(const void* g, void* l) {
  __builtin_amdgcn_global_load_lds(
      (const __attribute__((address_space(1))) uint32_t*)g,
      (__attribute__((address_space(3))) uint32_t*)l,
      16, 0, 0);
}

__device__ __forceinline__ int expert_of_row(const int* __restrict__ gs, int row) {
  int cum = 0, e = 0;
#pragma unroll
  for (int i = 0; i < NE; ++i) { if (row >= cum) e = i; cum += gs[i]; }
  return e;
}

// ---- k_prepA: lora_A -> Aoct[e][ko][c][8], scale folded. 256 blocks. ----
__global__ __launch_bounds__(256) void k_prepA(
    const float* __restrict__ lora_A, const float* __restrict__ lora_scaling,
    ushort* __restrict__ Aoct) {
  const int bid = blockIdx.x;
  const int tid = threadIdx.x;
  int u = bid * 4 + (tid >> 6);         // 0..1023 = e*128+ko
  int e = u >> 7, ko = u & 127;
  int c = tid & 63;
  int a = c >> 4, r = c & 15;
  float s = lora_scaling[a];
  ushort o8[8];
#pragma unroll
  for (int j = 0; j < 8; ++j) {
    float v = lora_A[((size_t)(a * NE + e) * DIN + ko * 8 + j) * RK + r];
    o8[j] = f2bf(s * v);
  }
  *(uint4*)(Aoct + ((size_t)((e * 128 + ko) * 64 + c)) * 8) = *(const uint4*)o8;
}

// ---- k_main: pure streaming packs ----
__global__ __launch_bounds__(256) void k_main(
    const float* __restrict__ x, ushort* __restrict__ xp,
    const float* __restrict__ weight, const float* __restrict__ lora_B,
    ushort* __restrict__ Boct) {
  const int bid = blockIdx.x;
  const int tid = threadIdx.x;

  if (bid < 1024) {
    // ======== pack x: 8 float4/thread, per-instruction coalesced ========
#pragma unroll
    for (int i = 0; i < 8; ++i) {
      int u = bid * 2048 + i * 256 + tid;         // float4 index
      float4 v = ((const float4*)x)[u];
      ushort4 b;
      b.x = f2bf(v.x); b.y = f2bf(v.y); b.z = f2bf(v.z); b.w = f2bf(v.w);
      ((ushort4*)xp)[u] = b;
    }
  } else {
    // ======== Boct pack ========
    int e, ko;
    const float* srcbase = nullptr;
    if (bid < 2048) {                     // W rows
      int u = bid - 1024;                 // 0..1023
      e = u >> 7; ko = u & 127;
      srcbase = weight + (size_t)e * DIN * DOUT + (size_t)(ko * 8) * DOUT;
    } else {                              // lora_B rows
      int u = bid - 2048;                 // 0..63
      e = u >> 3; int o = u & 7; ko = 128 + o;
    }
    int n4 = tid * 4;
    float v[8][4];
    if (bid < 2048) {
#pragma unroll
      for (int j = 0; j < 8; ++j) {
        float4 q = *(const float4*)(srcbase + (size_t)j * DOUT + n4);
        v[j][0] = q.x; v[j][1] = q.y; v[j][2] = q.z; v[j][3] = q.w;
      }
    } else {
      int o = ko - 128;
#pragma unroll
      for (int j = 0; j < 8; ++j) {
        int kv = o * 8 + j;
        int a = kv >> 4, r = kv & 15;
        float4 q = *(const float4*)(lora_B + (size_t)((a * NE + e) * RK + r) * DOUT + n4);
        v[j][0] = q.x; v[j][1] = q.y; v[j][2] = q.z; v[j][3] = q.w;
      }
    }
    ushort* dst = Boct + ((size_t)(e * NOCT + ko) * DOUT + n4) * 8;
#pragma unroll
    for (int i = 0; i < 4; ++i) {
      ushort o8[8];
#pragma unroll
      for (int j = 0; j < 8; ++j) o8[j] = f2bf(v[j][i]);
      *(uint4*)(dst + i * 8) = *(const uint4*)o8;
    }
  }
}

// ---- k_gemm: out[128x128] = [x|V](128 x 1088) @ Boct[e](1088 x 128) ----
// Double K-step, fused V with register-prefetched Aoct fragments.
__global__ __launch_bounds__(256) void k_gemm(
    const ushort* __restrict__ xp, const ushort* __restrict__ Boct,
    const ushort* __restrict__ Aoct,
    const int* __restrict__ gs, const int* __restrict__ adapter_idx,
    float* __restrict__ out) {
  __shared__ ushort As[2][128 * 64];      // 32 KB
  __shared__ ushort Bs[2][8 * 128 * 8];   // 32 KB

  const int tid = threadIdx.x;
  const int lane = tid & 63;
  const int wave = tid >> 6;
  const int wm = wave >> 1, wn = wave & 1;

  const int bid = blockIdx.x;                 // 0..511
  const int swz = (bid & 7) * 64 + (bid >> 3);  // bijective (512 % 8 == 0)
  const int row0 = (swz >> 3) * 128;
  const int n0 = (swz & 7) * 128;
  const int e = expert_of_row(gs, row0);
  const ushort* boct = Boct + (size_t)e * NOCT * DOUT * 8;
  const ushort* aocte = Aoct + (size_t)e * 128 * 64 * 8;

  f32x4 acc[4][4];
  f32x4 vacc[4][2];
#pragma unroll
  for (int mi = 0; mi < 4; ++mi) {
#pragma unroll
    for (int ni = 0; ni < 4; ++ni) acc[mi][ni] = (f32x4){0.f, 0.f, 0.f, 0.f};
    vacc[mi][0] = (f32x4){0.f, 0.f, 0.f, 0.f};
    vacc[mi][1] = (f32x4){0.f, 0.f, 0.f, 0.f};
  }

  const int r8 = lane >> 3;
  const int c8s = (lane & 7) ^ r8;              // swizzled source chunk

#define STAGE_TILE(hb, kt)                                                     \
  do {                                                                         \
    _Pragma("unroll")                                                          \
    for (int rd = 0; rd < 4; ++rd) {                                           \
      int r_ = wave * 32 + rd * 8 + r8;                                        \
      const ushort* src_ = xp + (size_t)(row0 + r_) * DIN + (kt) * 64 + c8s * 8; \
      gload_lds16(src_, &As[hb][(wave * 32 + rd * 8) * 64]);                   \
    }                                                                          \
    _Pragma("unroll")                                                          \
    for (int rd = 0; rd < 4; ++rd) {                                           \
      int u_ = wave * 4 + rd;                                                  \
      int o_ = u_ >> 1, hf_ = u_ & 1;                                          \
      const ushort* src_ =                                                     \
          boct + ((size_t)((kt) * 8 + o_) * DOUT + n0 + hf_ * 64 + lane) * 8;  \
      gload_lds16(src_, &Bs[hb][(o_ * 128 + hf_ * 64) * 8]);                   \
    }                                                                          \
  } while (0)

  // compute one BK=64 tile from buffer hb; V B-frags come from avr[t]
#define COMPUTE_TILE(hb, t)                                                    \
  do {                                                                         \
    _Pragma("unroll")                                                          \
    for (int h = 0; h < 2; ++h) {                                              \
      int kblk = h * 4 + (lane >> 4);                                          \
      short8 af[4], bfv[4];                                                    \
      _Pragma("unroll")                                                        \
      for (int mi = 0; mi < 4; ++mi) {                                         \
        int m_ = wm * 64 + mi * 16 + (lane & 15);                              \
        af[mi] = *(const short8*)&As[hb][m_ * 64 + (kblk ^ (m_ & 7)) * 8];     \
      }                                                                        \
      _Pragma("unroll")                                                        \
      for (int ni = 0; ni < 4; ++ni) {                                         \
        int n_ = wn * 64 + ni * 16 + (lane & 15);                              \
        bfv[ni] = *(const short8*)&Bs[hb][(kblk * 128 + n_) * 8];              \
      }                                                                        \
      _Pragma("unroll")                                                        \
      for (int mi = 0; mi < 4; ++mi)                                           \
        _Pragma("unroll")                                                      \
        for (int ni = 0; ni < 4; ++ni)                                         \
          acc[mi][ni] = __builtin_amdgcn_mfma_f32_16x16x32_bf16(               \
              af[mi], bfv[ni], acc[mi][ni], 0, 0, 0);                          \
      _Pragma("unroll")                                                        \
      for (int mi = 0; mi < 4; ++mi) {                                         \
        vacc[mi][0] = __builtin_amdgcn_mfma_f32_16x16x32_bf16(                 \
            af[mi], avr[t][h][0], vacc[mi][0], 0, 0, 0);                       \
        vacc[mi][1] = __builtin_amdgcn_mfma_f32_16x16x32_bf16(                 \
            af[mi], avr[t][h][1], vacc[mi][1], 0, 0, 0);                       \
      }                                                                        \
    }                                                                          \
  } while (0)

  for (int kp = 0; kp < 8; ++kp) {
    STAGE_TILE(0, kp * 2);
    STAGE_TILE(1, kp * 2 + 1);
    // T14: prefetch V B-frags for BOTH tiles to registers; the loads drain
    // under the same pre-barrier vmcnt the staging already pays for.
    short8 avr[2][2][2];
#pragma unroll
    for (int t = 0; t < 2; ++t) {
#pragma unroll
      for (int h = 0; h < 2; ++h) {
        int kblk = h * 4 + (lane >> 4);
        const ushort* base = aocte +
            ((size_t)((kp * 2 + t) * 8 + kblk) * 64 + wn * 32 + (lane & 15)) * 8;
        avr[t][h][0] = *(const short8*)(base);
        avr[t][h][1] = *(const short8*)(base + 16 * 8);
      }
    }
    __syncthreads();
    COMPUTE_TILE(0, 0);
    COMPUTE_TILE(1, 1);
    __syncthreads();
  }

#undef STAGE_TILE
#undef COMPUTE_TILE

  // ---- V tail (kt = 16) ----
#pragma unroll
  for (int rd = 0; rd < 4; ++rd) {
    int u = wave * 4 + rd;
    int o = u >> 1, hf = u & 1;
    const ushort* src = boct + ((size_t)(128 + o) * DOUT + n0 + hf * 64 + lane) * 8;
    gload_lds16(src, &Bs[0][(o * 128 + hf * 64) * 8]);
  }
  // write masked V (bf16) into As[0] with the XOR-swizzled layout:
  // LDS[row][cslot][j] = V[row][c], cslot = (c>>3)^(row&7), j = c&7
#pragma unroll
  for (int mi = 0; mi < 4; ++mi) {
#pragma unroll
    for (int i = 0; i < 4; ++i) {
      int rl = wm * 64 + mi * 16 + (lane >> 4) * 4 + i;
      int arow = adapter_idx[row0 + rl];
#pragma unroll
      for (int vi = 0; vi < 2; ++vi) {
        int c = wn * 32 + vi * 16 + (lane & 15);
        float val = (arow == (wn * 2 + vi)) ? vacc[mi][vi][i] : 0.f;
        As[0][rl * 64 + (((c >> 3) ^ (rl & 7)) * 8) + (c & 7)] = f2bf(val);
      }
    }
  }
  __syncthreads();

  // tail compute: A = V (K=64) from As[0], B = Bs[0]
#pragma unroll
  for (int h = 0; h < 2; ++h) {
    int kblk = h * 4 + (lane >> 4);
    short8 af[4], bfv[4];
#pragma unroll
    for (int mi = 0; mi < 4; ++mi) {
      int m = wm * 64 + mi * 16 + (lane & 15);
      af[mi] = *(const short8*)&As[0][m * 64 + (kblk ^ (m & 7)) * 8];
    }
#pragma unroll
    for (int ni = 0; ni < 4; ++ni) {
      int n = wn * 64 + ni * 16 + (lane & 15);
      bfv[ni] = *(const short8*)&Bs[0][(kblk * 128 + n) * 8];
    }
#pragma unroll
    for (int mi = 0; mi < 4; ++mi)
#pragma unroll
      for (int ni = 0; ni < 4; ++ni)
        acc[mi][ni] = __builtin_amdgcn_mfma_f32_16x16x32_bf16(
            af[mi], bfv[ni], acc[mi][ni], 0, 0, 0);
  }

  // epilogue: C layout col=lane&15, row=(lane>>4)*4+reg
#pragma unroll
  for (int mi = 0; mi < 4; ++mi) {
#pragma unroll
    for (int ni = 0; ni < 4; ++ni) {
      int col = n0 + wn * 64 + ni * 16 + (lane & 15);
#pragma unroll
      for (int i = 0; i < 4; ++i) {
        int r = row0 + wm * 64 + mi * 16 + (lane >> 4) * 4 + i;
        out[(size_t)r * DOUT + col] = acc[mi][ni][i];
      }
    }
  }
}

extern "C" void kernel_launch(void* const* d_in, const int* in_sizes, int n_in,
                              void* d_out, int out_size, void* d_ws, size_t ws_size,
                              hipStream_t stream) {
  const float* x            = (const float*)d_in[0];
  const float* weight       = (const float*)d_in[1];
  const float* lora_A       = (const float*)d_in[2];
  const float* lora_B       = (const float*)d_in[3];
  const float* lora_scaling = (const float*)d_in[4];
  const int*   group_sizes  = (const int*)d_in[5];
  const int*   adapter_idx  = (const int*)d_in[6];
  float* out = (float*)d_out;

  const size_t sz_xp   = (size_t)T_TOK * DIN * 2;               // 16.8 MB
  const size_t sz_boct = (size_t)NE * NOCT * DOUT * 8 * 2;      // 17.8 MB
  ushort* xp   = (ushort*)d_ws;
  ushort* boct = (ushort*)((char*)d_ws + sz_xp);
  ushort* aoct = (ushort*)((char*)d_ws + sz_xp + sz_boct);      // 1 MB

  k_prepA<<<256, 256, 0, stream>>>(lora_A, lora_scaling, aoct);
  k_main<<<2112, 256, 0, stream>>>(x, xp, weight, lora_B, boct);
  k_gemm<<<512, 256, 0, stream>>>(xp, boct, aoct, group_sizes, adapter_idx, out);
}

// Round 10
// 154.345 us; speedup vs baseline: 1.1398x; 1.1029x over previous
//
#include <hip/hip_runtime.h>
#include <hip/hip_bf16.h>
#include <stdint.h>

// LoRAExpert: out = ragged_dot(x, W, groups) + scale[a] * ((x @ A[a,e]) @ B[a,e])
// T=8192, D_IN=D_OUT=1024, E=8 (equal groups of 1024), A=4 adapters, R=16.
// Inputs fp32, output fp32. ws = 256 MiB.
//
// Round 15: un-fuse V from k_gemm (R14 post-mortem: fused-V = +50% MFMA,
// 4x redundant, 51us). k_gemm reverts to the R12 double-K form (best
// measured config). V gets a dedicated barrier-free design inside k_main:
// 512 blocks x 16 rows; 4 waves split K into quarters; per wave 8 chained
// iters of {x float4 loads, Aoct short8 loads (L2-hot), 4 MFMA} -- no LDS,
// no barriers in the loop; one end-barrier + 16KB LDS reduce over the 4
// K-quarters, adapter mask, write xp[:,1024:1088]. Fragment indexing is
// verbatim from the refchecked R11 V path.
//   k_prepA : lora_A -> Aoct (scale folded). 256 blocks.
//   k_main  : [0,512) V-blocks; [512,1536) x->xp[:, :1024] (stride KEXT);
//             [1536,2560) W->Boct; [2560,2624) lora_B->Boct.
//   k_gemm  : out = xp(K=1088) @ Boct[e]; 128x128, double K-step (R12).

#define T_TOK 8192
#define DIN   1024
#define DOUT  1024
#define NE    8
#define NA    4
#define RK    16
#define KEXT  1088      // 1024 + NA*RK
#define NOCT  136       // KEXT/8

typedef __attribute__((ext_vector_type(8))) short short8;
typedef __attribute__((ext_vector_type(4))) float f32x4;

__device__ __forceinline__ ushort f2bf(float f) {
  union { float f; uint32_t i; } v; v.f = f;
  uint32_t x = v.i;
  return (ushort)((x + 0x7fffu + ((x >> 16) & 1u)) >> 16);  // RNE
}

__device__ __forceinline__ void gload_lds16(const void* g, void* l) {
  __builtin_amdgcn_global_load_lds(
      (const __attribute__((address_space(1))) uint32_t*)g,
      (__attribute__((address_space(3))) uint32_t*)l,
      16, 0, 0);
}

__device__ __forceinline__ int expert_of_row(const int* __restrict__ gs, int row) {
  int cum = 0, e = 0;
#pragma unroll
  for (int i = 0; i < NE; ++i) { if (row >= cum) e = i; cum += gs[i]; }
  return e;
}

// ---- k_prepA: lora_A -> Aoct[e][ko][c][8], scale folded. 256 blocks. ----
// Aoct[((e*128+ko)*64 + c)*8 + j] = s_a * lora_A[a][e][ko*8+j][r], c = a*16+r.
__global__ __launch_bounds__(256) void k_prepA(
    const float* __restrict__ lora_A, const float* __restrict__ lora_scaling,
    ushort* __restrict__ Aoct) {
  const int bid = blockIdx.x;
  const int tid = threadIdx.x;
  int u = bid * 4 + (tid >> 6);         // 0..1023 = e*128+ko
  int e = u >> 7, ko = u & 127;
  int c = tid & 63;
  int a = c >> 4, r = c & 15;
  float s = lora_scaling[a];
  ushort o8[8];
#pragma unroll
  for (int j = 0; j < 8; ++j) {
    float v = lora_A[((size_t)(a * NE + e) * DIN + ko * 8 + j) * RK + r];
    o8[j] = f2bf(s * v);
  }
  *(uint4*)(Aoct + ((size_t)((e * 128 + ko) * 64 + c)) * 8) = *(const uint4*)o8;
}

// ---- k_main ----
// blocks [0,512)     : V-blocks (barrier-free K-quarter split + LDS reduce)
// blocks [512,1536)  : x -> xp[:, :1024]
// blocks [1536,2560) : W -> Boct
// blocks [2560,2624) : lora_B -> Boct
__global__ __launch_bounds__(256) void k_main(
    const float* __restrict__ x, ushort* __restrict__ xp,
    const ushort* __restrict__ Aoct,
    const float* __restrict__ weight, const float* __restrict__ lora_B,
    ushort* __restrict__ Boct,
    const int* __restrict__ gs, const int* __restrict__ adapter_idx) {
  __shared__ float vred[4][16][65];   // 16.6 KB (V reduce only)

  const int bid = blockIdx.x;
  const int tid = threadIdx.x;

  if (bid < 512) {
    // ======== V: rows [vb*16,+16), V = x @ (s*lora_A[e]) -> xp[:,1024:] ====
    const int vb = (bid & 7) * 64 + (bid >> 3);   // xcd k <- expert k
    const int lane = tid & 63;
    const int wave = tid >> 6;                    // K-quarter index
    const int rows0 = vb * 16;
    const int e = expert_of_row(gs, rows0);
    const int m = lane & 15;
    const int kg = lane >> 4;
    const ushort* aocte = Aoct + (size_t)e * 128 * 64 * 8;
    const float* xr = x + (size_t)(rows0 + m) * DIN;

    f32x4 acc[4];
#pragma unroll
    for (int a = 0; a < 4; ++a) acc[a] = (f32x4){0.f, 0.f, 0.f, 0.f};

    for (int kti = 0; kti < 8; ++kti) {
      const int kb = wave * 256 + kti * 32;       // K base of this MFMA
      const int k0 = kb + kg * 8;
      float4 a0 = *(const float4*)(xr + k0);
      float4 a1 = *(const float4*)(xr + k0 + 4);
      short8 af;
      af[0] = (short)f2bf(a0.x); af[1] = (short)f2bf(a0.y);
      af[2] = (short)f2bf(a0.z); af[3] = (short)f2bf(a0.w);
      af[4] = (short)f2bf(a1.x); af[5] = (short)f2bf(a1.y);
      af[6] = (short)f2bf(a1.z); af[7] = (short)f2bf(a1.w);
      const ushort* ab = aocte + ((size_t)(((kb >> 3) + kg) * 64) + m) * 8;
#pragma unroll
      for (int a = 0; a < 4; ++a) {
        short8 bf = *(const short8*)(ab + (size_t)(a * 16) * 8);
        acc[a] = __builtin_amdgcn_mfma_f32_16x16x32_bf16(af, bf, acc[a], 0, 0, 0);
      }
    }

    // reduce the 4 K-quarters; acc elem i -> row kg*4+i, col a*16+m (R11 map)
#pragma unroll
    for (int a = 0; a < 4; ++a)
#pragma unroll
      for (int i = 0; i < 4; ++i)
        vred[wave][kg * 4 + i][a * 16 + m] = acc[a][i];
    __syncthreads();

    int row = tid >> 4;
    int c0 = (tid & 15) * 4;
    float s0 = vred[0][row][c0]     + vred[1][row][c0]     + vred[2][row][c0]     + vred[3][row][c0];
    float s1 = vred[0][row][c0 + 1] + vred[1][row][c0 + 1] + vred[2][row][c0 + 1] + vred[3][row][c0 + 1];
    float s2 = vred[0][row][c0 + 2] + vred[1][row][c0 + 2] + vred[2][row][c0 + 2] + vred[3][row][c0 + 2];
    float s3 = vred[0][row][c0 + 3] + vred[1][row][c0 + 3] + vred[2][row][c0 + 3] + vred[3][row][c0 + 3];
    int arow = adapter_idx[rows0 + row];
    bool on = (arow == (c0 >> 4));              // c0..c0+3 share the adapter
    ushort4 b;
    b.x = f2bf(on ? s0 : 0.f);
    b.y = f2bf(on ? s1 : 0.f);
    b.z = f2bf(on ? s2 : 0.f);
    b.w = f2bf(on ? s3 : 0.f);
    *(ushort4*)(xp + (size_t)(rows0 + row) * KEXT + DIN + c0) = b;
  } else if (bid < 1536) {
    // ======== pack x -> xp[:, :1024] (stride KEXT) ========
#pragma unroll
    for (int i = 0; i < 8; ++i) {
      int u = (bid - 512) * 2048 + i * 256 + tid; // float4 index
      int row = u >> 8;                           // 256 float4 per row
      int c4 = u & 255;
      float4 v = *(const float4*)(x + (size_t)row * DIN + c4 * 4);
      ushort4 b;
      b.x = f2bf(v.x); b.y = f2bf(v.y); b.z = f2bf(v.z); b.w = f2bf(v.w);
      *(ushort4*)(xp + (size_t)row * KEXT + c4 * 4) = b;
    }
  } else {
    // ======== Boct pack ========
    int e, ko;
    const float* srcbase = nullptr;
    if (bid < 2560) {                     // W rows
      int u = bid - 1536;                 // 0..1023
      e = u >> 7; ko = u & 127;
      srcbase = weight + (size_t)e * DIN * DOUT + (size_t)(ko * 8) * DOUT;
    } else {                              // lora_B rows
      int u = bid - 2560;                 // 0..63
      e = u >> 3; int o = u & 7; ko = 128 + o;
    }
    int n4 = tid * 4;
    float v[8][4];
    if (bid < 2560) {
#pragma unroll
      for (int j = 0; j < 8; ++j) {
        float4 q = *(const float4*)(srcbase + (size_t)j * DOUT + n4);
        v[j][0] = q.x; v[j][1] = q.y; v[j][2] = q.z; v[j][3] = q.w;
      }
    } else {
      int o = ko - 128;
#pragma unroll
      for (int j = 0; j < 8; ++j) {
        int kv = o * 8 + j;
        int a = kv >> 4, r = kv & 15;
        float4 q = *(const float4*)(lora_B + (size_t)((a * NE + e) * RK + r) * DOUT + n4);
        v[j][0] = q.x; v[j][1] = q.y; v[j][2] = q.z; v[j][3] = q.w;
      }
    }
    ushort* dst = Boct + ((size_t)(e * NOCT + ko) * DOUT + n4) * 8;
#pragma unroll
    for (int i = 0; i < 4; ++i) {
      ushort o8[8];
#pragma unroll
      for (int j = 0; j < 8; ++j) o8[j] = f2bf(v[j][i]);
      *(uint4*)(dst + i * 8) = *(const uint4*)o8;
    }
  }
}

// ---- k_gemm: out[128x128] = xp(128 x 1088) @ Boct[e](1088 x 128) ----
// Double K-step: stage 2 x BK=64 tiles per barrier pair (As[2]/Bs[2]),
// compute both. 9 outer iters (8 double + 1 single). XCD-aware swizzle.
// (verbatim R12 -- best measured config)
__global__ __launch_bounds__(256) void k_gemm(
    const ushort* __restrict__ xp, const ushort* __restrict__ Boct,
    const int* __restrict__ gs, float* __restrict__ out) {
  __shared__ ushort As[2][128 * 64];      // 32 KB
  __shared__ ushort Bs[2][8 * 128 * 8];   // 32 KB

  const int tid = threadIdx.x;
  const int lane = tid & 63;
  const int wave = tid >> 6;
  const int wm = wave >> 1, wn = wave & 1;

  const int bid = blockIdx.x;                 // 0..511
  const int swz = (bid & 7) * 64 + (bid >> 3);  // bijective (512 % 8 == 0)
  const int row0 = (swz >> 3) * 128;
  const int n0 = (swz & 7) * 128;
  const int e = expert_of_row(gs, row0);
  const ushort* boct = Boct + (size_t)e * NOCT * DOUT * 8;

  f32x4 acc[4][4];
#pragma unroll
  for (int mi = 0; mi < 4; ++mi)
#pragma unroll
    for (int ni = 0; ni < 4; ++ni) acc[mi][ni] = (f32x4){0.f, 0.f, 0.f, 0.f};

  const int r8 = lane >> 3;
  const int c8s = (lane & 7) ^ r8;              // swizzled source chunk

#define STAGE_TILE(hb, kt)                                                     \
  do {                                                                         \
    _Pragma("unroll")                                                          \
    for (int rd = 0; rd < 4; ++rd) {                                           \
      int r_ = wave * 32 + rd * 8 + r8;                                        \
      const ushort* src_ = xp + (size_t)(row0 + r_) * KEXT + (kt) * 64 + c8s * 8; \
      gload_lds16(src_, &As[hb][(wave * 32 + rd * 8) * 64]);                   \
    }                                                                          \
    _Pragma("unroll")                                                          \
    for (int rd = 0; rd < 4; ++rd) {                                           \
      int u_ = wave * 4 + rd;                                                  \
      int o_ = u_ >> 1, hf_ = u_ & 1;                                          \
      const ushort* src_ =                                                     \
          boct + ((size_t)((kt) * 8 + o_) * DOUT + n0 + hf_ * 64 + lane) * 8;  \
      gload_lds16(src_, &Bs[hb][(o_ * 128 + hf_ * 64) * 8]);                   \
    }                                                                          \
  } while (0)

#define COMPUTE_TILE(hb)                                                       \
  do {                                                                         \
    _Pragma("unroll")                                                          \
    for (int h = 0; h < 2; ++h) {                                              \
      int kblk = h * 4 + (lane >> 4);                                          \
      short8 af[4], bfv[4];                                                    \
      _Pragma("unroll")                                                        \
      for (int mi = 0; mi < 4; ++mi) {                                         \
        int m_ = wm * 64 + mi * 16 + (lane & 15);                              \
        af[mi] = *(const short8*)&As[hb][m_ * 64 + (kblk ^ (m_ & 7)) * 8];     \
      }                                                                        \
      _Pragma("unroll")                                                        \
      for (int ni = 0; ni < 4; ++ni) {                                         \
        int n_ = wn * 64 + ni * 16 + (lane & 15);                              \
        bfv[ni] = *(const short8*)&Bs[hb][(kblk * 128 + n_) * 8];              \
      }                                                                        \
      _Pragma("unroll")                                                        \
      for (int mi = 0; mi < 4; ++mi)                                           \
        _Pragma("unroll")                                                      \
        for (int ni = 0; ni < 4; ++ni)                                         \
          acc[mi][ni] = __builtin_amdgcn_mfma_f32_16x16x32_bf16(               \
              af[mi], bfv[ni], acc[mi][ni], 0, 0, 0);                          \
    }                                                                          \
  } while (0)

  for (int kp = 0; kp < 8; ++kp) {
    STAGE_TILE(0, kp * 2);
    STAGE_TILE(1, kp * 2 + 1);
    __syncthreads();
    COMPUTE_TILE(0);
    COMPUTE_TILE(1);
    __syncthreads();
  }
  // tail: kt = 16 (the V slice)
  STAGE_TILE(0, 16);
  __syncthreads();
  COMPUTE_TILE(0);

#undef STAGE_TILE
#undef COMPUTE_TILE

  // epilogue: C layout col=lane&15, row=(lane>>4)*4+reg
#pragma unroll
  for (int mi = 0; mi < 4; ++mi) {
#pragma unroll
    for (int ni = 0; ni < 4; ++ni) {
      int col = n0 + wn * 64 + ni * 16 + (lane & 15);
#pragma unroll
      for (int i = 0; i < 4; ++i) {
        int r = row0 + wm * 64 + mi * 16 + (lane >> 4) * 4 + i;
        out[(size_t)r * DOUT + col] = acc[mi][ni][i];
      }
    }
  }
}

extern "C" void kernel_launch(void* const* d_in, const int* in_sizes, int n_in,
                              void* d_out, int out_size, void* d_ws, size_t ws_size,
                              hipStream_t stream) {
  const float* x            = (const float*)d_in[0];
  const float* weight       = (const float*)d_in[1];
  const float* lora_A       = (const float*)d_in[2];
  const float* lora_B       = (const float*)d_in[3];
  const float* lora_scaling = (const float*)d_in[4];
  const int*   group_sizes  = (const int*)d_in[5];
  const int*   adapter_idx  = (const int*)d_in[6];
  float* out = (float*)d_out;

  const size_t sz_xp   = (size_t)T_TOK * KEXT * 2;              // 17.8 MB
  const size_t sz_boct = (size_t)NE * NOCT * DOUT * 8 * 2;      // 17.8 MB
  ushort* xp   = (ushort*)d_ws;
  ushort* boct = (ushort*)((char*)d_ws + sz_xp);
  ushort* aoct = (ushort*)((char*)d_ws + sz_xp + sz_boct);      // 1 MB

  k_prepA<<<256, 256, 0, stream>>>(lora_A, lora_scaling, aoct);
  k_main<<<2624, 256, 0, stream>>>(x, xp, aoct, weight, lora_B, boct,
                                   group_sizes, adapter_idx);
  k_gemm<<<512, 256, 0, stream>>>(xp, boct, group_sizes, out);
}